// Round 1
// baseline (237.276 us; speedup 1.0000x reference)
//
#include <hip/hip_runtime.h>
#include <math.h>

#define Bb 16
#define Nn 2048
#define Dd 512
#define Kk 8

constexpr float TAU = 0.07f;
constexpr float EPSc = 1e-6f;
constexpr float LN_EPS = 1e-5f;
constexpr float NORM_EPS = 1e-12f;
constexpr float SCALE = 0.04419417382415922f; // 1/sqrt(512)

// output layout (floats)
constexpr size_t OUT_FFG  = 0;
constexpr size_t OUT_FBG  = (size_t)Bb*Nn*Dd;            // 16777216
constexpr size_t OUT_PBG  = OUT_FBG + (size_t)Bb*Nn*Dd;  // 33554432
constexpr size_t OUT_SSEM = OUT_PBG + (size_t)Bb*Kk*Dd;  // 33619968
constexpr size_t OUT_LOSS = OUT_SSEM + (size_t)Bb*Nn;    // 33652736

// ws layout (floats)
constexpr size_t WS_SCORES = 0;                              // B*K*N
constexpr size_t WS_PBPART = WS_SCORES + (size_t)Bb*Kk*Nn;   // B*8*K*D
constexpr size_t WS_M      = WS_PBPART + (size_t)Bb*8*Kk*Dd; // B*64
constexpr size_t WS_IDEN   = WS_M + Bb*64;                   // B*K
constexpr size_t WS_NP     = WS_IDEN + Bb*Kk;                // B*K
constexpr size_t WS_PART   = WS_NP + Bb*Kk;                  // 1024*68
constexpr int PART_STRIDE = 68;

// ---------------- K1: scores = q_bg . f_raw / sqrt(D) ----------------
__global__ __launch_bounds__(256) void k1_scores(const float* __restrict__ f_raw,
                                                 const float* __restrict__ q_bg,
                                                 float* __restrict__ ws) {
    __shared__ float qs[Kk*Dd];
    int b = blockIdx.x >> 6;
    int chunk = blockIdx.x & 63;
    for (int i = threadIdx.x; i < Kk*Dd; i += 256) qs[i] = q_bg[i];
    __syncthreads();
    int wave = threadIdx.x >> 6, lane = threadIdx.x & 63;
    for (int t = 0; t < 8; ++t) {
        int n = chunk*32 + wave*8 + t;
        const float* f = f_raw + ((size_t)b*Nn + n)*Dd;
        float fv[8];
        #pragma unroll
        for (int j = 0; j < 8; ++j) fv[j] = f[lane + 64*j];
        float acc[Kk];
        #pragma unroll
        for (int k = 0; k < Kk; ++k) {
            float a = 0.f;
            #pragma unroll
            for (int j = 0; j < 8; ++j) a += fv[j]*qs[k*Dd + lane + 64*j];
            acc[k] = a;
        }
        #pragma unroll
        for (int off = 32; off >= 1; off >>= 1) {
            #pragma unroll
            for (int k = 0; k < Kk; ++k) acc[k] += __shfl_xor(acc[k], off, 64);
        }
        #pragma unroll
        for (int k = 0; k < Kk; ++k)
            if (lane == k) ws[WS_SCORES + ((size_t)b*Kk + k)*Nn + n] = acc[k]*SCALE;
    }
}

// ---------------- K2: softmax over N per (b,k) ----------------
__global__ __launch_bounds__(256) void k2_softmax(float* __restrict__ ws) {
    int bk = blockIdx.x;
    float* s = ws + WS_SCORES + (size_t)bk*Nn;
    __shared__ float red[8];
    int tid = threadIdx.x, lane = tid & 63, wave = tid >> 6;
    float v[8];
    float mx = -1e30f;
    #pragma unroll
    for (int i = 0; i < 8; ++i) { v[i] = s[tid + 256*i]; mx = fmaxf(mx, v[i]); }
    #pragma unroll
    for (int off = 32; off >= 1; off >>= 1) mx = fmaxf(mx, __shfl_xor(mx, off, 64));
    if (lane == 0) red[wave] = mx;
    __syncthreads();
    mx = fmaxf(fmaxf(red[0], red[1]), fmaxf(red[2], red[3]));
    float sum = 0.f;
    #pragma unroll
    for (int i = 0; i < 8; ++i) { v[i] = expf(v[i]-mx); sum += v[i]; }
    #pragma unroll
    for (int off = 32; off >= 1; off >>= 1) sum += __shfl_xor(sum, off, 64);
    if (lane == 0) red[4+wave] = sum;
    __syncthreads();
    float inv = 1.f/(red[4]+red[5]+red[6]+red[7]);
    #pragma unroll
    for (int i = 0; i < 8; ++i) s[tid + 256*i] = v[i]*inv;
}

// ---------------- K3: p_bg partials over N-chunks ----------------
__global__ __launch_bounds__(256) void k3_pbpart(const float* __restrict__ f_raw,
                                                 float* __restrict__ ws) {
    int b = blockIdx.x, ns = blockIdx.y, dc = blockIdx.z;
    int d = dc*256 + threadIdx.x;
    __shared__ float at[Kk][256];
    for (int e = threadIdx.x, it = 0; it < Kk; ++it, e += 256) {
        int k = e >> 8, nn = e & 255;
        at[k][nn] = ws[WS_SCORES + ((size_t)b*Kk + k)*Nn + ns*256 + nn];
    }
    __syncthreads();
    float acc[Kk] = {0,0,0,0,0,0,0,0};
    for (int nn = 0; nn < 256; ++nn) {
        int n = ns*256 + nn;
        float f = f_raw[((size_t)b*Nn + n)*Dd + d];
        #pragma unroll
        for (int k = 0; k < Kk; ++k) acc[k] += at[k][nn]*f;
    }
    #pragma unroll
    for (int k = 0; k < Kk; ++k)
        ws[WS_PBPART + ((size_t)(b*8 + ns)*Kk + k)*Dd + d] = acc[k];
}

// ---------------- K3b: reduce partials -> p_bg, M, 1/denom, ||p|| ----------------
__global__ __launch_bounds__(256) void k3b_pbg(float* __restrict__ ws,
                                               float* __restrict__ out_pbg) {
    int b = blockIdx.x;
    __shared__ float pb[Kk*Dd];
    for (int e = threadIdx.x; e < Kk*Dd; e += 256) {
        float s = 0.f;
        #pragma unroll
        for (int ns = 0; ns < 8; ++ns)
            s += ws[WS_PBPART + (size_t)(b*8 + ns)*(Kk*Dd) + e];
        pb[e] = s;
        out_pbg[(size_t)b*Kk*Dd + e] = s;
    }
    __syncthreads();
    if (threadIdx.x < 64) {
        int k1 = threadIdx.x >> 3, k2 = threadIdx.x & 7;
        float m = 0.f;
        for (int d = 0; d < Dd; ++d) m += pb[k1*Dd+d]*pb[k2*Dd+d];
        ws[WS_M + b*64 + threadIdx.x] = m;
        if (k1 == k2) {
            ws[WS_IDEN + b*Kk + k1] = 1.f/(m + EPSc);
            ws[WS_NP + b*Kk + k1] = sqrtf(m);
        }
    }
}

// ---------------- K5: per-token fused main ----------------
__global__ __launch_bounds__(256) void k5_main(
    const float* __restrict__ f_raw, const float* __restrict__ f_q,
    const int* __restrict__ gt_mask, const float* __restrict__ alpha_p,
    const float* __restrict__ ln_w, const float* __restrict__ ln_b,
    const float* __restrict__ pbg, float* __restrict__ ws,
    float* __restrict__ out_ffg, float* __restrict__ out_fbg,
    float* __restrict__ out_ssem)
{
    __shared__ float pb[Kk*Dd];
    __shared__ float wl[Dd], blds[Dd], fqn[Dd];
    __shared__ float Ml[64], idenl[Kk], inpl[Kk];
    __shared__ float Swave[4][64];
    __shared__ float scal[4][4];
    __shared__ float rtmp[4];

    int b = blockIdx.x >> 6;
    int chunk = blockIdx.x & 63;
    int tid = threadIdx.x, lane = tid & 63, wave = tid >> 6;

    for (int e = tid; e < Kk*Dd; e += 256) pb[e] = pbg[(size_t)b*Kk*Dd + e];
    for (int e = tid; e < Dd; e += 256) { wl[e] = ln_w[e]; blds[e] = ln_b[e]; }
    if (tid < 64) Ml[tid] = ws[WS_M + b*64 + tid];
    if (tid < Kk) {
        idenl[tid] = ws[WS_IDEN + b*Kk + tid];
        inpl[tid]  = 1.f/fmaxf(ws[WS_NP + b*Kk + tid], NORM_EPS);
    }
    float fq0 = f_q[b*Dd + tid], fq1 = f_q[b*Dd + tid + 256];
    float p2 = fq0*fq0 + fq1*fq1;
    #pragma unroll
    for (int off = 32; off >= 1; off >>= 1) p2 += __shfl_xor(p2, off, 64);
    if (lane == 0) rtmp[wave] = p2;
    __syncthreads();
    float invq = 1.f/fmaxf(sqrtf(rtmp[0]+rtmp[1]+rtmp[2]+rtmp[3]), NORM_EPS);
    fqn[tid] = fq0*invq; fqn[tid+256] = fq1*invq;
    float alpha = alpha_p[0];
    __syncthreads();

    float S_acc = 0.f;
    int pi = lane >> 3, pj = lane & 7;
    float compact_acc = 0.f, diag_acc = 0.f, align_s = 0.f, align_c = 0.f;

    for (int t = 0; t < 8; ++t) {
        int n = chunk*32 + wave*8 + t;
        size_t rowoff = ((size_t)b*Nn + n)*Dd;
        float fv[8];
        #pragma unroll
        for (int j = 0; j < 8; ++j) fv[j] = f_raw[rowoff + lane + 64*j];
        float acc[Kk]; float nf2 = 0.f;
        #pragma unroll
        for (int k = 0; k < Kk; ++k) {
            float a = 0.f;
            #pragma unroll
            for (int j = 0; j < 8; ++j) a += fv[j]*pb[k*Dd + lane + 64*j];
            acc[k] = a;
        }
        #pragma unroll
        for (int j = 0; j < 8; ++j) nf2 += fv[j]*fv[j];
        #pragma unroll
        for (int off = 32; off >= 1; off >>= 1) {
            #pragma unroll
            for (int k = 0; k < Kk; ++k) acc[k] += __shfl_xor(acc[k], off, 64);
            nf2 += __shfl_xor(nf2, off, 64);
        }
        float coef[Kk];
        #pragma unroll
        for (int k = 0; k < Kk; ++k) coef[k] = acc[k]*idenl[k];
        float fb[8]; float nb2 = 0.f;
        #pragma unroll
        for (int j = 0; j < 8; ++j) {
            float s = 0.f;
            #pragma unroll
            for (int k = 0; k < Kk; ++k) s += coef[k]*pb[k*Dd + lane + 64*j];
            fb[j] = s; out_fbg[rowoff + lane + 64*j] = s;
        }
        float xv[8]; float sx = 0.f;
        #pragma unroll
        for (int j = 0; j < 8; ++j) { xv[j] = fv[j] - alpha*fb[j]; sx += xv[j]; nb2 += fb[j]*fb[j]; }
        #pragma unroll
        for (int off = 32; off >= 1; off >>= 1) { sx += __shfl_xor(sx, off, 64); nb2 += __shfl_xor(nb2, off, 64); }
        float mu = sx * (1.f/Dd);
        float sv = 0.f;
        #pragma unroll
        for (int j = 0; j < 8; ++j) { float dl = xv[j]-mu; sv += dl*dl; }
        #pragma unroll
        for (int off = 32; off >= 1; off >>= 1) sv += __shfl_xor(sv, off, 64);
        float rstd = 1.f/sqrtf(sv*(1.f/Dd) + LN_EPS);
        float ng2 = 0.f, dotq = 0.f;
        #pragma unroll
        for (int j = 0; j < 8; ++j) {
            int d = lane + 64*j;
            float g = (xv[j]-mu)*rstd*wl[d] + blds[d];
            out_ffg[rowoff + d] = g;
            ng2 += g*g; dotq += g*fqn[d];
        }
        #pragma unroll
        for (int off = 32; off >= 1; off >>= 1) { ng2 += __shfl_xor(ng2, off, 64); dotq += __shfl_xor(dotq, off, 64); }
        float sim = dotq / fmaxf(sqrtf(ng2), NORM_EPS);
        float ssem = 1.f/(1.f + expf(-sim*(1.f/TAU)));
        if (lane == 0) out_ssem[(size_t)b*Nn + n] = ssem;
        // compact
        float invnf = 1.f/fmaxf(sqrtf(nf2), NORM_EPS);
        float cmin = 1e30f;
        #pragma unroll
        for (int k = 0; k < Kk; ++k) {
            float c = acc[k]*invnf*inpl[k];
            cmin = fminf(cmin, 1.f - c);
        }
        compact_acc += cmin;
        // orth: c' = coef/max(||f_bg||,eps)
        float invnb = 1.f/fmaxf(sqrtf(nb2), NORM_EPS);
        float cp[Kk];
        #pragma unroll
        for (int k = 0; k < Kk; ++k) cp[k] = coef[k]*invnb;
        float gnn = 0.f;
        #pragma unroll
        for (int i = 0; i < Kk; ++i) {
            float s = 0.f;
            #pragma unroll
            for (int j2 = 0; j2 < Kk; ++j2) s += cp[j2]*Ml[i*8+j2];
            gnn += cp[i]*s;
        }
        diag_acc += gnn*gnn;
        float cpi = 0.f, cpj = 0.f;
        #pragma unroll
        for (int k = 0; k < Kk; ++k) { cpi = (pi==k)?cp[k]:cpi; cpj = (pj==k)?cp[k]:cpj; }
        S_acc += cpi*cpj;
        // align
        int m = gt_mask[b*Nn + n];
        if (m != 0) { align_s += -logf(fmaxf(ssem, EPSc)); align_c += 1.f; }
    }

    Swave[wave][lane] = S_acc;
    if (lane == 0) { scal[wave][0]=compact_acc; scal[wave][1]=diag_acc; scal[wave][2]=align_s; scal[wave][3]=align_c; }
    __syncthreads();
    float* part = ws + WS_PART + (size_t)blockIdx.x*PART_STRIDE;
    if (tid < 64) part[tid] = Swave[0][tid]+Swave[1][tid]+Swave[2][tid]+Swave[3][tid];
    if (tid >= 64 && tid < 68) {
        int q = tid-64;
        part[64+q] = scal[0][q]+scal[1][q]+scal[2][q]+scal[3][q];
    }
}

// ---------------- K6: finalize losses ----------------
__global__ __launch_bounds__(256) void k6_final(const float* __restrict__ ws,
                                                float* __restrict__ out_loss) {
    __shared__ float Sall[Bb*64];
    __shared__ double trb[Bb];
    int tid = threadIdx.x;
    for (int e = tid; e < Bb*64; e += 256) {
        int b = e >> 6, pair = e & 63;
        float s = 0.f;
        for (int c = 0; c < 64; ++c)
            s += ws[WS_PART + (size_t)(b*64 + c)*PART_STRIDE + pair];
        Sall[e] = s;
    }
    __syncthreads();
    if (tid < Bb) {
        int b = tid;
        double A[8][8];
        for (int i = 0; i < 8; ++i)
            for (int j = 0; j < 8; ++j) {
                double s = 0.0;
                for (int k = 0; k < 8; ++k)
                    s += (double)ws[WS_M + b*64 + i*8 + k] * (double)Sall[b*64 + k*8 + j];
                A[i][j] = s;
            }
        double tr = 0.0;
        for (int i = 0; i < 8; ++i)
            for (int j = 0; j < 8; ++j) tr += A[i][j]*A[j][i];
        trb[b] = tr;
    }
    __syncthreads();
    if (tid == 0) {
        double compact = 0, diag = 0, asum = 0, acnt = 0, trtot = 0;
        for (int bl = 0; bl < Bb*64; ++bl) {
            const float* p = ws + WS_PART + (size_t)bl*PART_STRIDE;
            compact += p[64]; diag += p[65]; asum += p[66]; acnt += p[67];
        }
        for (int b = 0; b < Bb; ++b) trtot += trb[b];
        out_loss[0] = (float)(compact / (double)((size_t)Bb*Nn));
        out_loss[1] = (float)((trtot - diag) / ((double)Bb*(double)Nn*(double)Nn));
        out_loss[2] = (float)(acnt > 0 ? asum / (acnt > 1.0 ? acnt : 1.0) : 0.0);
    }
}

extern "C" void kernel_launch(void* const* d_in, const int* in_sizes, int n_in,
                              void* d_out, int out_size, void* d_ws, size_t ws_size,
                              hipStream_t stream) {
    (void)in_sizes; (void)n_in; (void)out_size; (void)ws_size;
    const float* f_raw   = (const float*)d_in[0];
    const float* f_q     = (const float*)d_in[1];
    const int*   gt_mask = (const int*)d_in[2];
    const float* q_bg    = (const float*)d_in[3];
    const float* alpha   = (const float*)d_in[4];
    const float* ln_w    = (const float*)d_in[5];
    const float* ln_b    = (const float*)d_in[6];
    float* out = (float*)d_out;
    float* ws  = (float*)d_ws;

    k1_scores<<<Bb*(Nn/32), 256, 0, stream>>>(f_raw, q_bg, ws);
    k2_softmax<<<Bb*Kk, 256, 0, stream>>>(ws);
    k3_pbpart<<<dim3(Bb, 8, 2), 256, 0, stream>>>(f_raw, ws);
    k3b_pbg<<<Bb, 256, 0, stream>>>(ws, out + OUT_PBG);
    k5_main<<<Bb*(Nn/32), 256, 0, stream>>>(f_raw, f_q, gt_mask, alpha, ln_w, ln_b,
                                            out + OUT_PBG, ws,
                                            out + OUT_FFG, out + OUT_FBG, out + OUT_SSEM);
    k6_final<<<1, 256, 0, stream>>>(ws, out + OUT_LOSS);
}

// Round 2
// 205.576 us; speedup vs baseline: 1.1542x; 1.1542x over previous
//
#include <hip/hip_runtime.h>
#include <math.h>

#define Bb 16
#define Nn 2048
#define Dd 512
#define Kk 8

constexpr float TAU = 0.07f;
constexpr float EPSc = 1e-6f;
constexpr float LN_EPS = 1e-5f;
constexpr float NORM_EPS = 1e-12f;
constexpr float SCALE = 0.04419417382415922f; // 1/sqrt(512)

// output layout (floats)
constexpr size_t OUT_FFG  = 0;
constexpr size_t OUT_FBG  = (size_t)Bb*Nn*Dd;
constexpr size_t OUT_PBG  = OUT_FBG + (size_t)Bb*Nn*Dd;
constexpr size_t OUT_SSEM = OUT_PBG + (size_t)Bb*Kk*Dd;
constexpr size_t OUT_LOSS = OUT_SSEM + (size_t)Bb*Nn;

// ws layout (floats)
constexpr int    NSCH = 32;                 // k3 N-chunks of 64 tokens
constexpr size_t WS_SCORES = 0;                                   // B*K*N
constexpr size_t WS_PBPART = WS_SCORES + (size_t)Bb*Kk*Nn;        // B*NSCH*K*D
constexpr size_t WS_M      = WS_PBPART + (size_t)Bb*NSCH*Kk*Dd;   // B*64
constexpr size_t WS_IDEN   = WS_M + Bb*64;                        // B*K
constexpr size_t WS_INP    = WS_IDEN + Bb*Kk;                     // B*K
constexpr size_t WS_P1     = WS_INP + Bb*Kk;                      // B*K
constexpr size_t WS_FQN    = WS_P1 + Bb*Kk;                       // B*D
constexpr size_t WS_PART   = WS_FQN + (size_t)Bb*Dd;              // 2048*68
constexpr int PART_STRIDE = 68;
constexpr int K5_BLOCKS = Bb*Nn/16;         // 2048, 128 per batch
constexpr size_t WS_BSUM   = WS_PART + (size_t)K5_BLOCKS*PART_STRIDE; // B*68

__device__ __forceinline__ float dot4(float4 a, float4 b) {
    return a.x*b.x + a.y*b.y + a.z*b.z + a.w*b.w;
}

// ---------------- K1: scores = q_bg . f_raw / sqrt(D) ----------------
__global__ __launch_bounds__(256) void k1_scores(const float* __restrict__ f_raw,
                                                 const float* __restrict__ q_bg,
                                                 float* __restrict__ ws) {
    int b = blockIdx.x >> 7;
    int chunk = blockIdx.x & 127;
    int lane = threadIdx.x & 63, wave = threadIdx.x >> 6;
    float4 qr[Kk][2];
    #pragma unroll
    for (int k = 0; k < Kk; ++k) {
        qr[k][0] = *(const float4*)(q_bg + k*Dd + lane*4);
        qr[k][1] = *(const float4*)(q_bg + k*Dd + 256 + lane*4);
    }
    for (int t = 0; t < 4; ++t) {
        int n = chunk*16 + wave*4 + t;
        const float* f = f_raw + ((size_t)b*Nn + n)*Dd;
        float4 fv0 = *(const float4*)(f + lane*4);
        float4 fv1 = *(const float4*)(f + 256 + lane*4);
        float a[Kk];
        #pragma unroll
        for (int k = 0; k < Kk; ++k) a[k] = dot4(fv0, qr[k][0]) + dot4(fv1, qr[k][1]);
        #pragma unroll
        for (int off = 32; off >= 1; off >>= 1) {
            #pragma unroll
            for (int k = 0; k < Kk; ++k) a[k] += __shfl_xor(a[k], off, 64);
        }
        float sv = a[0];
        #pragma unroll
        for (int k = 1; k < Kk; ++k) if (lane == k) sv = a[k];
        if (lane < Kk) ws[WS_SCORES + ((size_t)b*Kk + lane)*Nn + n] = sv*SCALE;
    }
}

// ---------------- K2: softmax over N per (b,k) ----------------
__global__ __launch_bounds__(256) void k2_softmax(float* __restrict__ ws) {
    int bk = blockIdx.x;
    float* s = ws + WS_SCORES + (size_t)bk*Nn;
    __shared__ float red[8];
    int tid = threadIdx.x, lane = tid & 63, wave = tid >> 6;
    float v[8];
    float mx = -1e30f;
    #pragma unroll
    for (int i = 0; i < 8; ++i) { v[i] = s[tid + 256*i]; mx = fmaxf(mx, v[i]); }
    #pragma unroll
    for (int off = 32; off >= 1; off >>= 1) mx = fmaxf(mx, __shfl_xor(mx, off, 64));
    if (lane == 0) red[wave] = mx;
    __syncthreads();
    mx = fmaxf(fmaxf(red[0], red[1]), fmaxf(red[2], red[3]));
    float sum = 0.f;
    #pragma unroll
    for (int i = 0; i < 8; ++i) { v[i] = expf(v[i]-mx); sum += v[i]; }
    #pragma unroll
    for (int off = 32; off >= 1; off >>= 1) sum += __shfl_xor(sum, off, 64);
    if (lane == 0) red[4+wave] = sum;
    __syncthreads();
    float inv = 1.f/(red[4]+red[5]+red[6]+red[7]);
    #pragma unroll
    for (int i = 0; i < 8; ++i) s[tid + 256*i] = v[i]*inv;
}

// ---------------- K3: p_bg partials over N-chunks ----------------
__global__ __launch_bounds__(256) void k3_pbpart(const float* __restrict__ f_raw,
                                                 float* __restrict__ ws) {
    int b = blockIdx.x, ns = blockIdx.y, dh = blockIdx.z;
    int d = dh*256 + threadIdx.x;
    __shared__ float at[Kk][64];
    for (int e = threadIdx.x; e < Kk*64; e += 256) {
        int k = e >> 6, nn = e & 63;
        at[k][nn] = ws[WS_SCORES + ((size_t)b*Kk + k)*Nn + ns*64 + nn];
    }
    __syncthreads();
    float acc[Kk] = {0,0,0,0,0,0,0,0};
    const float* fp = f_raw + ((size_t)b*Nn + ns*64)*Dd + d;
    #pragma unroll 4
    for (int nn = 0; nn < 64; ++nn) {
        float f = fp[(size_t)nn*Dd];
        #pragma unroll
        for (int k = 0; k < Kk; ++k) acc[k] += at[k][nn]*f;
    }
    #pragma unroll
    for (int k = 0; k < Kk; ++k)
        ws[WS_PBPART + ((size_t)(b*NSCH + ns)*Kk + k)*Dd + d] = acc[k];
}

// ---------------- K3b: reduce partials -> p_bg, M, iden, inp, P1, fqn ----------------
__global__ __launch_bounds__(256) void k3b_pbg(float* __restrict__ ws,
                                               float* __restrict__ out_pbg,
                                               const float* __restrict__ f_q) {
    int b = blockIdx.x, tid = threadIdx.x;
    int lane = tid & 63, wave = tid >> 6;
    __shared__ float pb[Kk*Dd];
    __shared__ float mseg[64][4];
    __shared__ float p1seg[8][8];
    __shared__ float red[4];
    for (int e = tid; e < Kk*Dd; e += 256) {
        float s = 0.f;
        #pragma unroll 8
        for (int ns = 0; ns < NSCH; ++ns)
            s += ws[WS_PBPART + (size_t)(b*NSCH + ns)*(Kk*Dd) + e];
        pb[e] = s;
        out_pbg[(size_t)b*Kk*Dd + e] = s;
    }
    float q0 = f_q[b*Dd + tid], q1 = f_q[b*Dd + 256 + tid];
    float p2 = q0*q0 + q1*q1;
    #pragma unroll
    for (int off = 32; off >= 1; off >>= 1) p2 += __shfl_xor(p2, off, 64);
    if (lane == 0) red[wave] = p2;
    __syncthreads();   // pb + red ready
    float invq = 1.f/fmaxf(sqrtf(red[0]+red[1]+red[2]+red[3]), NORM_EPS);
    ws[WS_FQN + b*Dd + tid] = q0*invq;
    ws[WS_FQN + b*Dd + 256 + tid] = q1*invq;
    {
        int pair = tid >> 2, seg = tid & 3;
        int i = pair >> 3, j = pair & 7;
        float s = 0.f;
        for (int d = seg*128; d < seg*128 + 128; ++d) s += pb[i*Dd + d]*pb[j*Dd + d];
        mseg[pair][seg] = s;
    }
    if (tid < 64) {
        int k = tid >> 3, sg = tid & 7;
        float s1 = 0.f;
        for (int d = sg*64; d < sg*64 + 64; ++d) s1 += pb[k*Dd + d];
        p1seg[k][sg] = s1;
    }
    __syncthreads();
    if (tid < 64) {
        float m = mseg[tid][0] + mseg[tid][1] + mseg[tid][2] + mseg[tid][3];
        ws[WS_M + b*64 + tid] = m;
        if ((tid >> 3) == (tid & 7)) {
            int k = tid & 7;
            ws[WS_IDEN + b*Kk + k] = 1.f/(m + EPSc);
            ws[WS_INP + b*Kk + k] = 1.f/fmaxf(sqrtf(m), NORM_EPS);
        }
    }
    if (tid < 8) {
        float s1 = 0.f;
        #pragma unroll
        for (int sg = 0; sg < 8; ++sg) s1 += p1seg[tid][sg];
        ws[WS_P1 + b*Kk + tid] = s1;
    }
}

// ---------------- K5: per-token fused main ----------------
__global__ __launch_bounds__(256) void k5_main(
    const float* __restrict__ f_raw,
    const int* __restrict__ gt_mask, const float* __restrict__ alpha_p,
    const float* __restrict__ ln_w, const float* __restrict__ ln_b,
    const float* __restrict__ pbg, float* __restrict__ ws,
    float* __restrict__ out_ffg, float* __restrict__ out_fbg,
    float* __restrict__ out_ssem)
{
    __shared__ __align__(16) float wl[Dd];
    __shared__ __align__(16) float bl[Dd];
    __shared__ __align__(16) float fq[Dd];
    __shared__ float Ml[64];
    __shared__ float idenl[Kk], inpl[Kk], p1l[Kk];
    __shared__ float Swave[4][64];
    __shared__ float scal[4][4];

    int b = blockIdx.x >> 7;
    int chunk = blockIdx.x & 127;
    int tid = threadIdx.x, lane = tid & 63, wave = tid >> 6;

    for (int e = tid; e < Dd; e += 256) {
        wl[e] = ln_w[e]; bl[e] = ln_b[e]; fq[e] = ws[WS_FQN + b*Dd + e];
    }
    if (tid < 64) Ml[tid] = ws[WS_M + b*64 + tid];
    if (tid < Kk) {
        idenl[tid] = ws[WS_IDEN + b*Kk + tid];
        inpl[tid]  = ws[WS_INP + b*Kk + tid];
        p1l[tid]   = ws[WS_P1 + b*Kk + tid];
    }
    float4 pbr[Kk][2];
    #pragma unroll
    for (int k = 0; k < Kk; ++k) {
        pbr[k][0] = *(const float4*)(pbg + (size_t)b*Kk*Dd + k*Dd + lane*4);
        pbr[k][1] = *(const float4*)(pbg + (size_t)b*Kk*Dd + k*Dd + 256 + lane*4);
    }
    float alpha = alpha_p[0];
    __syncthreads();

    float S_acc = 0.f, compact_acc = 0.f, diag_acc = 0.f, align_s = 0.f, align_c = 0.f;
    int pi = lane >> 3, pj = lane & 7;

    for (int t = 0; t < 4; ++t) {
        int n = chunk*16 + wave*4 + t;
        size_t rowoff = ((size_t)b*Nn + n)*Dd;
        float4 fv0 = *(const float4*)(f_raw + rowoff + lane*4);
        float4 fv1 = *(const float4*)(f_raw + rowoff + 256 + lane*4);
        // chain 1: 10 simultaneous dots
        float a[Kk];
        #pragma unroll
        for (int k = 0; k < Kk; ++k) a[k] = dot4(fv0, pbr[k][0]) + dot4(fv1, pbr[k][1]);
        float nf2 = dot4(fv0, fv0) + dot4(fv1, fv1);
        float sfv = fv0.x+fv0.y+fv0.z+fv0.w + fv1.x+fv1.y+fv1.z+fv1.w;
        #pragma unroll
        for (int off = 32; off >= 1; off >>= 1) {
            #pragma unroll
            for (int k = 0; k < Kk; ++k) a[k] += __shfl_xor(a[k], off, 64);
            nf2 += __shfl_xor(nf2, off, 64);
            sfv += __shfl_xor(sfv, off, 64);
        }
        // lane-uniform scalar math
        float coef[Kk], sca = 0.f, sp1 = 0.f;
        #pragma unroll
        for (int k = 0; k < Kk; ++k) {
            coef[k] = a[k]*idenl[k]; sca += coef[k]*a[k]; sp1 += coef[k]*p1l[k];
        }
        float quad = 0.f;
        #pragma unroll
        for (int i = 0; i < Kk; ++i) {
            float ti = 0.f;
            #pragma unroll
            for (int j = 0; j < Kk; ++j) ti += Ml[i*8 + j]*coef[j];
            quad += coef[i]*ti;
        }
        float sx  = sfv - alpha*sp1;
        float sxx = nf2 - 2.f*alpha*sca + alpha*alpha*quad;
        float mu  = sx*(1.f/Dd);
        float var = sxx*(1.f/Dd) - mu*mu;
        float rstd = 1.f/sqrtf(var + LN_EPS);
        // compact
        float invnf = 1.f/fmaxf(sqrtf(nf2), NORM_EPS);
        float cmin = 1e30f;
        #pragma unroll
        for (int k = 0; k < Kk; ++k) cmin = fminf(cmin, 1.f - a[k]*invnf*inpl[k]);
        compact_acc += cmin;
        // orth (nb2 == quad exactly)
        float invnb = 1.f/fmaxf(sqrtf(quad), NORM_EPS);
        float inb2 = invnb*invnb;
        float gnn = quad*inb2;
        diag_acc += gnn*gnn;
        float cpi = coef[0], cpj = coef[0];
        #pragma unroll
        for (int k = 1; k < Kk; ++k) { if (pi == k) cpi = coef[k]; if (pj == k) cpj = coef[k]; }
        S_acc += cpi*cpj*inb2;
        // phase 2: fb, x, g + chain 2
        float ng2 = 0.f, dotq = 0.f;
        #pragma unroll
        for (int r = 0; r < 2; ++r) {
            float4 fvr = r ? fv1 : fv0;
            float4 fb = {0.f, 0.f, 0.f, 0.f};
            #pragma unroll
            for (int k = 0; k < Kk; ++k) {
                float4 p = pbr[k][r];
                fb.x += coef[k]*p.x; fb.y += coef[k]*p.y;
                fb.z += coef[k]*p.z; fb.w += coef[k]*p.w;
            }
            int d0 = r*256 + lane*4;
            *(float4*)(out_fbg + rowoff + d0) = fb;
            float4 x4;
            x4.x = fvr.x - alpha*fb.x; x4.y = fvr.y - alpha*fb.y;
            x4.z = fvr.z - alpha*fb.z; x4.w = fvr.w - alpha*fb.w;
            float4 w4 = *(const float4*)(&wl[d0]);
            float4 b4 = *(const float4*)(&bl[d0]);
            float4 q4 = *(const float4*)(&fq[d0]);
            float4 g;
            g.x = (x4.x - mu)*rstd*w4.x + b4.x;
            g.y = (x4.y - mu)*rstd*w4.y + b4.y;
            g.z = (x4.z - mu)*rstd*w4.z + b4.z;
            g.w = (x4.w - mu)*rstd*w4.w + b4.w;
            *(float4*)(out_ffg + rowoff + d0) = g;
            ng2 += dot4(g, g); dotq += dot4(g, q4);
        }
        #pragma unroll
        for (int off = 32; off >= 1; off >>= 1) {
            ng2 += __shfl_xor(ng2, off, 64); dotq += __shfl_xor(dotq, off, 64);
        }
        float sim = dotq*(1.f/fmaxf(sqrtf(ng2), NORM_EPS));
        float ssem = 1.f/(1.f + expf(-sim*(1.f/TAU)));
        if (lane == 0) out_ssem[(size_t)b*Nn + n] = ssem;
        int m = gt_mask[b*Nn + n];
        if (m != 0) { align_s += -logf(fmaxf(ssem, EPSc)); align_c += 1.f; }
    }

    Swave[wave][lane] = S_acc;
    if (lane == 0) { scal[wave][0]=compact_acc; scal[wave][1]=diag_acc; scal[wave][2]=align_s; scal[wave][3]=align_c; }
    __syncthreads();
    float* part = ws + WS_PART + (size_t)blockIdx.x*PART_STRIDE;
    if (tid < 64) part[tid] = Swave[0][tid]+Swave[1][tid]+Swave[2][tid]+Swave[3][tid];
    if (tid >= 64 && tid < 68) {
        int q = tid - 64;
        part[64+q] = scal[0][q]+scal[1][q]+scal[2][q]+scal[3][q];
    }
}

// ---------------- K6a: per-batch partial reduce ----------------
__global__ __launch_bounds__(256) void k6a_reduce(float* __restrict__ ws) {
    int b = blockIdx.x, tid = threadIdx.x;
    if (tid < PART_STRIDE) {
        float s = 0.f;
        #pragma unroll 4
        for (int c = 0; c < 128; ++c)
            s += ws[WS_PART + (size_t)(b*128 + c)*PART_STRIDE + tid];
        ws[WS_BSUM + (size_t)b*PART_STRIDE + tid] = s;
    }
}

// ---------------- K6b: finalize losses ----------------
__global__ __launch_bounds__(64) void k6b_final(const float* __restrict__ ws,
                                                float* __restrict__ out_loss) {
    __shared__ double trb[Bb];
    int tid = threadIdx.x;
    if (tid < Bb) {
        int b = tid;
        double A[8][8];
        for (int i = 0; i < 8; ++i)
            for (int j = 0; j < 8; ++j) {
                double s = 0.0;
                for (int k = 0; k < 8; ++k)
                    s += (double)ws[WS_M + b*64 + i*8 + k] *
                         (double)ws[WS_BSUM + (size_t)b*PART_STRIDE + k*8 + j];
                A[i][j] = s;
            }
        double tr = 0.0;
        for (int i = 0; i < 8; ++i)
            for (int j = 0; j < 8; ++j) tr += A[i][j]*A[j][i];
        trb[b] = tr;
    }
    __syncthreads();
    if (tid == 0) {
        double compact = 0, diag = 0, asum = 0, acnt = 0, trtot = 0;
        for (int b = 0; b < Bb; ++b) {
            const float* p = ws + WS_BSUM + (size_t)b*PART_STRIDE;
            compact += p[64]; diag += p[65]; asum += p[66]; acnt += p[67];
            trtot += trb[b];
        }
        out_loss[0] = (float)(compact / (double)((size_t)Bb*Nn));
        out_loss[1] = (float)((trtot - diag) / ((double)Bb*(double)Nn*(double)Nn));
        out_loss[2] = (float)(acnt > 0 ? asum / (acnt > 1.0 ? acnt : 1.0) : 0.0);
    }
}

extern "C" void kernel_launch(void* const* d_in, const int* in_sizes, int n_in,
                              void* d_out, int out_size, void* d_ws, size_t ws_size,
                              hipStream_t stream) {
    (void)in_sizes; (void)n_in; (void)out_size; (void)ws_size;
    const float* f_raw   = (const float*)d_in[0];
    const float* f_q     = (const float*)d_in[1];
    const int*   gt_mask = (const int*)d_in[2];
    const float* q_bg    = (const float*)d_in[3];
    const float* alpha   = (const float*)d_in[4];
    const float* ln_w    = (const float*)d_in[5];
    const float* ln_b    = (const float*)d_in[6];
    float* out = (float*)d_out;
    float* ws  = (float*)d_ws;

    k1_scores<<<K5_BLOCKS, 256, 0, stream>>>(f_raw, q_bg, ws);
    k2_softmax<<<Bb*Kk, 256, 0, stream>>>(ws);
    k3_pbpart<<<dim3(Bb, NSCH, 2), 256, 0, stream>>>(f_raw, ws);
    k3b_pbg<<<Bb, 256, 0, stream>>>(ws, out + OUT_PBG, f_q);
    k5_main<<<K5_BLOCKS, 256, 0, stream>>>(f_raw, gt_mask, alpha, ln_w, ln_b,
                                           out + OUT_PBG, ws,
                                           out + OUT_FFG, out + OUT_FBG, out + OUT_SSEM);
    k6a_reduce<<<Bb, 256, 0, stream>>>(ws);
    k6b_final<<<1, 64, 0, stream>>>(ws, out + OUT_LOSS);
}

// Round 4
// 176.078 us; speedup vs baseline: 1.3476x; 1.1675x over previous
//
#include <hip/hip_runtime.h>
#include <math.h>

#define Bb 16
#define Nn 2048
#define Dd 512
#define Kk 8

constexpr float TAU = 0.07f;
constexpr float EPSc = 1e-6f;
constexpr float LN_EPS = 1e-5f;
constexpr float NORM_EPS = 1e-12f;
constexpr float SCALE = 0.04419417382415922f; // 1/sqrt(512)

// output layout (floats)
constexpr size_t OUT_FFG  = 0;
constexpr size_t OUT_FBG  = (size_t)Bb*Nn*Dd;
constexpr size_t OUT_PBG  = OUT_FBG + (size_t)Bb*Nn*Dd;
constexpr size_t OUT_SSEM = OUT_PBG + (size_t)Bb*Kk*Dd;
constexpr size_t OUT_LOSS = OUT_SSEM + (size_t)Bb*Nn;

// ws layout (floats)
constexpr int    NSCH = 32;
constexpr size_t WS_SC     = 0;                               // B*N*8  scores [b][n][k]
constexpr size_t WS_NF2    = WS_SC + (size_t)Bb*Nn*Kk;        // B*N
constexpr size_t WS_SF     = WS_NF2 + (size_t)Bb*Nn;          // B*N
constexpr size_t WS_PBPART = WS_SF + (size_t)Bb*Nn;           // B*NSCH*K*D (2M)
constexpr size_t WS_REC    = WS_PBPART;                       // alias, used after k3b: B*N*16
constexpr size_t WS_CP     = WS_REC + (size_t)Bb*Nn*16;       // alias: B*N*8
constexpr size_t WS_M      = WS_PBPART + (size_t)Bb*NSCH*Kk*Dd;
constexpr size_t WS_IDEN   = WS_M + Bb*64;
constexpr size_t WS_INP    = WS_IDEN + Bb*Kk;
constexpr size_t WS_P1     = WS_INP + Bb*Kk;
constexpr size_t WS_FQN    = WS_P1 + Bb*Kk;                   // B*D
constexpr size_t WS_P5A    = WS_FQN + (size_t)Bb*Dd;          // 512*2
constexpr size_t WS_P5B    = WS_P5A + 1024;                   // 512*2
constexpr size_t WS_TRB    = WS_P5B + 1024;                   // 16

__device__ __forceinline__ float dot4(float4 a, float4 b) {
    return a.x*b.x + a.y*b.y + a.z*b.z + a.w*b.w;
}

// ============ K1: token-per-lane scores + nf2/sf ============
__global__ __launch_bounds__(256) void k1_scores(const float* __restrict__ f_raw,
                                                 const float* __restrict__ q_bg,
                                                 float* __restrict__ ws) {
    int b = blockIdx.x >> 5;
    int tok0 = (blockIdx.x & 31) * 64;
    int tid = threadIdx.x, lane = tid & 63, wave = tid >> 6;
    __shared__ float tile[4][64*36];
    __shared__ float part[4][64][12];
    float* mt = tile[wave];
    int dw = __builtin_amdgcn_readfirstlane(wave * 128);
    const float* qb = q_bg + dw;                       // scalar base
    const float* frow = f_raw + (size_t)b*Nn*Dd + dw;
    int tg = lane >> 3, c4 = (lane & 7) * 4;

    float acc[8] = {0,0,0,0,0,0,0,0};
    float nf2 = 0.f, sf = 0.f;

    float4 cur[8], nxt[8];
    #pragma unroll
    for (int i = 0; i < 8; ++i)
        cur[i] = *(const float4*)(frow + (size_t)(tok0 + i*8 + tg)*Dd + c4);

    #pragma unroll
    for (int sub = 0; sub < 4; ++sub) {
        if (sub < 3) {
            #pragma unroll
            for (int i = 0; i < 8; ++i)
                nxt[i] = *(const float4*)(frow + (size_t)(tok0 + i*8 + tg)*Dd + (sub+1)*32 + c4);
        }
        #pragma unroll
        for (int i = 0; i < 8; ++i)
            *(float4*)&mt[(i*8 + tg)*36 + c4] = cur[i];
        #pragma unroll
        for (int cc = 0; cc < 8; ++cc) {
            float4 f4 = *(const float4*)&mt[lane*36 + cc*4];
            const float* qd = qb + sub*32 + cc*4;      // uniform -> s_load
            #pragma unroll
            for (int k = 0; k < 8; ++k) {
                acc[k] += f4.x*qd[k*Dd+0] + f4.y*qd[k*Dd+1]
                        + f4.z*qd[k*Dd+2] + f4.w*qd[k*Dd+3];
            }
            nf2 += dot4(f4, f4);
            sf  += f4.x + f4.y + f4.z + f4.w;
        }
        if (sub < 3) {
            #pragma unroll
            for (int i = 0; i < 8; ++i) cur[i] = nxt[i];
        }
    }
    *(float4*)&part[wave][lane][0] = make_float4(acc[0],acc[1],acc[2],acc[3]);
    *(float4*)&part[wave][lane][4] = make_float4(acc[4],acc[5],acc[6],acc[7]);
    *(float2*)&part[wave][lane][8] = make_float2(nf2, sf);
    __syncthreads();
    if (wave == 0) {
        float a[8] = {0,0,0,0,0,0,0,0};
        float n2 = 0.f, s1 = 0.f;
        #pragma unroll
        for (int w = 0; w < 4; ++w) {
            float4 p0 = *(const float4*)&part[w][lane][0];
            float4 p1 = *(const float4*)&part[w][lane][4];
            float2 p2 = *(const float2*)&part[w][lane][8];
            a[0]+=p0.x; a[1]+=p0.y; a[2]+=p0.z; a[3]+=p0.w;
            a[4]+=p1.x; a[5]+=p1.y; a[6]+=p1.z; a[7]+=p1.w;
            n2 += p2.x; s1 += p2.y;
        }
        size_t n = (size_t)b*Nn + tok0 + lane;
        *(float4*)(ws + WS_SC + n*8)     = make_float4(a[0]*SCALE,a[1]*SCALE,a[2]*SCALE,a[3]*SCALE);
        *(float4*)(ws + WS_SC + n*8 + 4) = make_float4(a[4]*SCALE,a[5]*SCALE,a[6]*SCALE,a[7]*SCALE);
        ws[WS_NF2 + n] = n2;
        ws[WS_SF + n]  = s1;
    }
}

// ============ K2: softmax over N per (b,k), [n][k] layout ============
__global__ __launch_bounds__(256) void k2_softmax(float* __restrict__ ws) {
    int b = blockIdx.x, tid = threadIdx.x, lane = tid & 63, wave = tid >> 6;
    float* sc = ws + WS_SC + (size_t)b*Nn*8;
    __shared__ float redm[4][8];
    __shared__ float reds[4][8];
    float4 v[4][4];
    float mx[8];
    #pragma unroll
    for (int k = 0; k < 8; ++k) mx[k] = -3.4e38f;
    #pragma unroll
    for (int r = 0; r < 4; ++r) {
        int base = r*4096 + tid*16;
        #pragma unroll
        for (int q = 0; q < 4; ++q) v[r][q] = *(const float4*)(sc + base + q*4);
        mx[0]=fmaxf(mx[0],fmaxf(v[r][0].x,v[r][2].x)); mx[1]=fmaxf(mx[1],fmaxf(v[r][0].y,v[r][2].y));
        mx[2]=fmaxf(mx[2],fmaxf(v[r][0].z,v[r][2].z)); mx[3]=fmaxf(mx[3],fmaxf(v[r][0].w,v[r][2].w));
        mx[4]=fmaxf(mx[4],fmaxf(v[r][1].x,v[r][3].x)); mx[5]=fmaxf(mx[5],fmaxf(v[r][1].y,v[r][3].y));
        mx[6]=fmaxf(mx[6],fmaxf(v[r][1].z,v[r][3].z)); mx[7]=fmaxf(mx[7],fmaxf(v[r][1].w,v[r][3].w));
    }
    #pragma unroll
    for (int off = 32; off >= 1; off >>= 1) {
        #pragma unroll
        for (int k = 0; k < 8; ++k) mx[k] = fmaxf(mx[k], __shfl_xor(mx[k], off, 64));
    }
    if (lane == 0) {
        #pragma unroll
        for (int k = 0; k < 8; ++k) redm[wave][k] = mx[k];
    }
    __syncthreads();
    #pragma unroll
    for (int k = 0; k < 8; ++k)
        mx[k] = fmaxf(fmaxf(redm[0][k],redm[1][k]), fmaxf(redm[2][k],redm[3][k]));
    float sm[8] = {0,0,0,0,0,0,0,0};
    #pragma unroll
    for (int r = 0; r < 4; ++r) {
        v[r][0].x=expf(v[r][0].x-mx[0]); v[r][0].y=expf(v[r][0].y-mx[1]);
        v[r][0].z=expf(v[r][0].z-mx[2]); v[r][0].w=expf(v[r][0].w-mx[3]);
        v[r][1].x=expf(v[r][1].x-mx[4]); v[r][1].y=expf(v[r][1].y-mx[5]);
        v[r][1].z=expf(v[r][1].z-mx[6]); v[r][1].w=expf(v[r][1].w-mx[7]);
        v[r][2].x=expf(v[r][2].x-mx[0]); v[r][2].y=expf(v[r][2].y-mx[1]);
        v[r][2].z=expf(v[r][2].z-mx[2]); v[r][2].w=expf(v[r][2].w-mx[3]);
        v[r][3].x=expf(v[r][3].x-mx[4]); v[r][3].y=expf(v[r][3].y-mx[5]);
        v[r][3].z=expf(v[r][3].z-mx[6]); v[r][3].w=expf(v[r][3].w-mx[7]);
        sm[0]+=v[r][0].x+v[r][2].x; sm[1]+=v[r][0].y+v[r][2].y;
        sm[2]+=v[r][0].z+v[r][2].z; sm[3]+=v[r][0].w+v[r][2].w;
        sm[4]+=v[r][1].x+v[r][3].x; sm[5]+=v[r][1].y+v[r][3].y;
        sm[6]+=v[r][1].z+v[r][3].z; sm[7]+=v[r][1].w+v[r][3].w;
    }
    #pragma unroll
    for (int off = 32; off >= 1; off >>= 1) {
        #pragma unroll
        for (int k = 0; k < 8; ++k) sm[k] += __shfl_xor(sm[k], off, 64);
    }
    if (lane == 0) {
        #pragma unroll
        for (int k = 0; k < 8; ++k) reds[wave][k] = sm[k];
    }
    __syncthreads();
    float inv[8];
    #pragma unroll
    for (int k = 0; k < 8; ++k)
        inv[k] = 1.f/(reds[0][k]+reds[1][k]+reds[2][k]+reds[3][k]);
    #pragma unroll
    for (int r = 0; r < 4; ++r) {
        int base = r*4096 + tid*16;
        v[r][0].x*=inv[0]; v[r][0].y*=inv[1]; v[r][0].z*=inv[2]; v[r][0].w*=inv[3];
        v[r][1].x*=inv[4]; v[r][1].y*=inv[5]; v[r][1].z*=inv[6]; v[r][1].w*=inv[7];
        v[r][2].x*=inv[0]; v[r][2].y*=inv[1]; v[r][2].z*=inv[2]; v[r][2].w*=inv[3];
        v[r][3].x*=inv[4]; v[r][3].y*=inv[5]; v[r][3].z*=inv[6]; v[r][3].w*=inv[7];
        #pragma unroll
        for (int q = 0; q < 4; ++q) *(float4*)(sc + base + q*4) = v[r][q];
    }
}

// ============ K3: p_bg partials ============
__global__ __launch_bounds__(256) void k3_pbpart(const float* __restrict__ f_raw,
                                                 float* __restrict__ ws) {
    int b = blockIdx.x, ns = blockIdx.y, dh = blockIdx.z;
    int tid = threadIdx.x;
    __shared__ float at[64*8];
    for (int e = tid; e < 512; e += 256)
        at[e] = ws[WS_SC + ((size_t)b*Nn + ns*64)*8 + e];
    __syncthreads();
    int d = dh*256 + tid;
    float acc[8] = {0,0,0,0,0,0,0,0};
    const float* fp = f_raw + ((size_t)b*Nn + ns*64)*Dd + d;
    for (int nn = 0; nn < 64; ++nn) {
        float f = fp[(size_t)nn*Dd];
        float4 a0 = *(const float4*)&at[nn*8];
        float4 a1 = *(const float4*)&at[nn*8+4];
        acc[0]+=a0.x*f; acc[1]+=a0.y*f; acc[2]+=a0.z*f; acc[3]+=a0.w*f;
        acc[4]+=a1.x*f; acc[5]+=a1.y*f; acc[6]+=a1.z*f; acc[7]+=a1.w*f;
    }
    #pragma unroll
    for (int k = 0; k < 8; ++k)
        ws[WS_PBPART + ((size_t)(b*NSCH + ns)*Kk + k)*Dd + d] = acc[k];
}

// ============ K3b: reduce -> p_bg, M, iden, inp, P1, fqn ============
__global__ __launch_bounds__(256) void k3b_pbg(float* __restrict__ ws,
                                               float* __restrict__ out_pbg,
                                               const float* __restrict__ f_q) {
    int b = blockIdx.x, tid = threadIdx.x;
    int lane = tid & 63, wave = tid >> 6;
    __shared__ float pb[Kk*Dd];
    __shared__ float mseg[64][4];
    __shared__ float p1seg[8][8];
    __shared__ float red[4];
    for (int e = tid; e < Kk*Dd; e += 256) {
        float s = 0.f;
        #pragma unroll 8
        for (int ns = 0; ns < NSCH; ++ns)
            s += ws[WS_PBPART + (size_t)(b*NSCH + ns)*(Kk*Dd) + e];
        pb[e] = s;
        out_pbg[(size_t)b*Kk*Dd + e] = s;
    }
    float q0 = f_q[b*Dd + tid], q1 = f_q[b*Dd + 256 + tid];
    float p2 = q0*q0 + q1*q1;
    #pragma unroll
    for (int off = 32; off >= 1; off >>= 1) p2 += __shfl_xor(p2, off, 64);
    if (lane == 0) red[wave] = p2;
    __syncthreads();
    float invq = 1.f/fmaxf(sqrtf(red[0]+red[1]+red[2]+red[3]), NORM_EPS);
    ws[WS_FQN + b*Dd + tid] = q0*invq;
    ws[WS_FQN + b*Dd + 256 + tid] = q1*invq;
    {
        int pair = tid >> 2, seg = tid & 3;
        int i = pair >> 3, j = pair & 7;
        float s = 0.f;
        for (int d = seg*128; d < seg*128 + 128; ++d) s += pb[i*Dd + d]*pb[j*Dd + d];
        mseg[pair][seg] = s;
    }
    if (tid < 64) {
        int k = tid >> 3, sg = tid & 7;
        float s1 = 0.f;
        for (int d = sg*64; d < sg*64 + 64; ++d) s1 += pb[k*Dd + d];
        p1seg[k][sg] = s1;
    }
    __syncthreads();
    if (tid < 64) {
        float m = mseg[tid][0] + mseg[tid][1] + mseg[tid][2] + mseg[tid][3];
        ws[WS_M + b*64 + tid] = m;
        if ((tid >> 3) == (tid & 7)) {
            int k = tid & 7;
            ws[WS_IDEN + b*Kk + k] = 1.f/(m + EPSc);
            ws[WS_INP + b*Kk + k] = 1.f/fmaxf(sqrtf(m), NORM_EPS);
        }
    }
    if (tid < 8) {
        float s1 = 0.f;
        #pragma unroll
        for (int sg = 0; sg < 8; ++sg) s1 += p1seg[tid][sg];
        ws[WS_P1 + b*Kk + tid] = s1;
    }
}

// ============ K5a: token-per-lane dots + per-token scalars ============
__global__ __launch_bounds__(256) void k5a_scal(const float* __restrict__ f_raw,
                                                const float* __restrict__ alpha_p,
                                                const float* __restrict__ pbg,
                                                float* __restrict__ ws) {
    int b = blockIdx.x >> 5;
    int tok0 = (blockIdx.x & 31) * 64;
    int tid = threadIdx.x, lane = tid & 63, wave = tid >> 6;
    __shared__ float tile[4][64*36];
    __shared__ float part[4][64][8];
    float* mt = tile[wave];
    int dw = __builtin_amdgcn_readfirstlane(wave * 128);
    const float* pbb = pbg + (size_t)b*Kk*Dd + dw;      // uniform base
    const float* frow = f_raw + (size_t)b*Nn*Dd + dw;
    int tg = lane >> 3, c4 = (lane & 7) * 4;

    float acc[8] = {0,0,0,0,0,0,0,0};
    float4 cur[8], nxt[8];
    #pragma unroll
    for (int i = 0; i < 8; ++i)
        cur[i] = *(const float4*)(frow + (size_t)(tok0 + i*8 + tg)*Dd + c4);

    #pragma unroll
    for (int sub = 0; sub < 4; ++sub) {
        if (sub < 3) {
            #pragma unroll
            for (int i = 0; i < 8; ++i)
                nxt[i] = *(const float4*)(frow + (size_t)(tok0 + i*8 + tg)*Dd + (sub+1)*32 + c4);
        }
        #pragma unroll
        for (int i = 0; i < 8; ++i)
            *(float4*)&mt[(i*8 + tg)*36 + c4] = cur[i];
        #pragma unroll
        for (int cc = 0; cc < 8; ++cc) {
            float4 f4 = *(const float4*)&mt[lane*36 + cc*4];
            const float* pd = pbb + sub*32 + cc*4;      // uniform -> s_load
            #pragma unroll
            for (int k = 0; k < 8; ++k) {
                acc[k] += f4.x*pd[k*Dd+0] + f4.y*pd[k*Dd+1]
                        + f4.z*pd[k*Dd+2] + f4.w*pd[k*Dd+3];
            }
        }
        if (sub < 3) {
            #pragma unroll
            for (int i = 0; i < 8; ++i) cur[i] = nxt[i];
        }
    }
    *(float4*)&part[wave][lane][0] = make_float4(acc[0],acc[1],acc[2],acc[3]);
    *(float4*)&part[wave][lane][4] = make_float4(acc[4],acc[5],acc[6],acc[7]);
    __syncthreads();
    if (wave == 0) {
        float a[8] = {0,0,0,0,0,0,0,0};
        #pragma unroll
        for (int w = 0; w < 4; ++w) {
            float4 p0 = *(const float4*)&part[w][lane][0];
            float4 p1 = *(const float4*)&part[w][lane][4];
            a[0]+=p0.x; a[1]+=p0.y; a[2]+=p0.z; a[3]+=p0.w;
            a[4]+=p1.x; a[5]+=p1.y; a[6]+=p1.z; a[7]+=p1.w;
        }
        size_t n = (size_t)b*Nn + tok0 + lane;
        float nf2 = ws[WS_NF2 + n];
        float sf  = ws[WS_SF + n];
        const float* Mw  = ws + WS_M + b*64;
        const float* idw = ws + WS_IDEN + b*8;
        const float* inw = ws + WS_INP + b*8;
        const float* p1w = ws + WS_P1 + b*8;
        float alpha = alpha_p[0];
        float coef[8], sca = 0.f, sp1 = 0.f;
        #pragma unroll
        for (int k = 0; k < 8; ++k) {
            coef[k] = a[k]*idw[k];
            sca += coef[k]*a[k];
            sp1 += coef[k]*p1w[k];
        }
        float quad = 0.f;
        #pragma unroll
        for (int i = 0; i < 8; ++i) {
            float ti = 0.f;
            #pragma unroll
            for (int j = 0; j < 8; ++j) ti += Mw[i*8+j]*coef[j];
            quad += coef[i]*ti;
        }
        float sx  = sf - alpha*sp1;
        float sxx = nf2 - 2.f*alpha*sca + alpha*alpha*quad;
        float mu  = sx*(1.f/Dd);
        float var = sxx*(1.f/Dd) - mu*mu;
        float rstd = 1.f/sqrtf(fmaxf(var, 0.f) + LN_EPS);
        float invnf = 1.f/fmaxf(sqrtf(nf2), NORM_EPS);
        float cmin = 1e30f;
        #pragma unroll
        for (int k = 0; k < 8; ++k) cmin = fminf(cmin, 1.f - a[k]*invnf*inw[k]);
        float invnb = 1.f/fmaxf(sqrtf(quad), NORM_EPS);
        float inb2 = invnb*invnb;
        float gnn = quad*inb2;
        float dsum = gnn*gnn;
        *(float4*)(ws + WS_REC + n*16)     = make_float4(coef[0],coef[1],coef[2],coef[3]);
        *(float4*)(ws + WS_REC + n*16 + 4) = make_float4(coef[4],coef[5],coef[6],coef[7]);
        *(float4*)(ws + WS_REC + n*16 + 8) = make_float4(mu, rstd, 0.f, 0.f);
        *(float4*)(ws + WS_CP + n*8)     = make_float4(coef[0]*invnb,coef[1]*invnb,coef[2]*invnb,coef[3]*invnb);
        *(float4*)(ws + WS_CP + n*8 + 4) = make_float4(coef[4]*invnb,coef[5]*invnb,coef[6]*invnb,coef[7]*invnb);
        float csum = cmin;
        #pragma unroll
        for (int off = 32; off >= 1; off >>= 1) {
            csum += __shfl_xor(csum, off, 64);
            dsum += __shfl_xor(dsum, off, 64);
        }
        if (lane == 0) {
            ws[WS_P5A + (size_t)blockIdx.x*2 + 0] = csum;
            ws[WS_P5A + (size_t)blockIdx.x*2 + 1] = dsum;
        }
    }
}

// ============ K5b: elementwise fb / LN / g / ssem (memory-bound) ============
__global__ __launch_bounds__(256) void k5b_elem(
    const float* __restrict__ f_raw, const int* __restrict__ gt_mask,
    const float* __restrict__ alpha_p, const float* __restrict__ ln_w,
    const float* __restrict__ ln_b, const float* __restrict__ pbg,
    float* __restrict__ ws, float* __restrict__ out_ffg,
    float* __restrict__ out_fbg, float* __restrict__ out_ssem)
{
    int b = blockIdx.x >> 5;
    int tok0 = (blockIdx.x & 31) * 64;
    int tid = threadIdx.x, lane = tid & 63, wave = tid >> 6;
    __shared__ float al[4][2];
    int d0 = lane*4, d1 = 256 + lane*4;
    float4 pbr[8][2];
    #pragma unroll
    for (int k = 0; k < 8; ++k) {
        pbr[k][0] = *(const float4*)(pbg + (size_t)b*Kk*Dd + k*Dd + d0);
        pbr[k][1] = *(const float4*)(pbg + (size_t)b*Kk*Dd + k*Dd + d1);
    }
    float4 w0 = *(const float4*)(ln_w + d0), w1 = *(const float4*)(ln_w + d1);
    float4 b0 = *(const float4*)(ln_b + d0), b1 = *(const float4*)(ln_b + d1);
    float4 q0 = *(const float4*)(ws + WS_FQN + b*Dd + d0);
    float4 q1 = *(const float4*)(ws + WS_FQN + b*Dd + d1);
    float alpha = alpha_p[0];
    const float* rcb = ws + WS_REC + (size_t)b*Nn*16;
    float align_s = 0.f, align_c = 0.f;
    int wbase = tok0 + wave*16;
    for (int t = 0; t < 16; ++t) {
        int tok = wbase + t;
        size_t n = (size_t)b*Nn + tok;
        int ro = __builtin_amdgcn_readfirstlane(tok * 16);
        float c[8];
        #pragma unroll
        for (int k = 0; k < 8; ++k) c[k] = rcb[ro + k];
        float muv  = rcb[ro + 8];
        float rstd = rcb[ro + 9];
        size_t rowoff = n*(size_t)Dd;
        float4 fv0 = *(const float4*)(f_raw + rowoff + d0);
        float4 fv1 = *(const float4*)(f_raw + rowoff + d1);
        float ng2 = 0.f, dq = 0.f;
        {
            float4 fb = {0,0,0,0};
            #pragma unroll
            for (int k = 0; k < 8; ++k) {
                float4 p = pbr[k][0];
                fb.x += c[k]*p.x; fb.y += c[k]*p.y; fb.z += c[k]*p.z; fb.w += c[k]*p.w;
            }
            *(float4*)(out_fbg + rowoff + d0) = fb;
            float4 g;
            g.x = (fv0.x - alpha*fb.x - muv)*rstd*w0.x + b0.x;
            g.y = (fv0.y - alpha*fb.y - muv)*rstd*w0.y + b0.y;
            g.z = (fv0.z - alpha*fb.z - muv)*rstd*w0.z + b0.z;
            g.w = (fv0.w - alpha*fb.w - muv)*rstd*w0.w + b0.w;
            *(float4*)(out_ffg + rowoff + d0) = g;
            ng2 += dot4(g, g); dq += dot4(g, q0);
        }
        {
            float4 fb = {0,0,0,0};
            #pragma unroll
            for (int k = 0; k < 8; ++k) {
                float4 p = pbr[k][1];
                fb.x += c[k]*p.x; fb.y += c[k]*p.y; fb.z += c[k]*p.z; fb.w += c[k]*p.w;
            }
            *(float4*)(out_fbg + rowoff + d1) = fb;
            float4 g;
            g.x = (fv1.x - alpha*fb.x - muv)*rstd*w1.x + b1.x;
            g.y = (fv1.y - alpha*fb.y - muv)*rstd*w1.y + b1.y;
            g.z = (fv1.z - alpha*fb.z - muv)*rstd*w1.z + b1.z;
            g.w = (fv1.w - alpha*fb.w - muv)*rstd*w1.w + b1.w;
            *(float4*)(out_ffg + rowoff + d1) = g;
            ng2 += dot4(g, g); dq += dot4(g, q1);
        }
        #pragma unroll
        for (int off = 32; off >= 1; off >>= 1) {
            ng2 += __shfl_xor(ng2, off, 64);
            dq  += __shfl_xor(dq,  off, 64);
        }
        float sim = dq * (1.f/fmaxf(sqrtf(ng2), NORM_EPS));
        float ssem = 1.f/(1.f + expf(-sim*(1.f/TAU)));
        if (lane == 0) {
            out_ssem[n] = ssem;
            if (gt_mask[n] != 0) { align_s += -logf(fmaxf(ssem, EPSc)); align_c += 1.f; }
        }
    }
    if (lane == 0) { al[wave][0] = align_s; al[wave][1] = align_c; }
    __syncthreads();
    if (tid == 0) {
        ws[WS_P5B + (size_t)blockIdx.x*2 + 0] = al[0][0]+al[1][0]+al[2][0]+al[3][0];
        ws[WS_P5B + (size_t)blockIdx.x*2 + 1] = al[0][1]+al[1][1]+al[2][1]+al[3][1];
    }
}

// ============ K6s: per-batch S = sum cp cp^T, then tr((M S)^2) ============
__global__ __launch_bounds__(256) void k6s_gram(float* __restrict__ ws) {
    int b = blockIdx.x, tid = threadIdx.x;
    __shared__ float cps[256*8];
    __shared__ float Sred[4][64];
    __shared__ float Sfull[64];
    __shared__ float Alds[64];
    __shared__ float Mlds[64];
    int pr = tid & 63, g = tid >> 6;
    int i = pr >> 3, j = pr & 7;
    float s = 0.f;
    for (int tile = 0; tile < 8; ++tile) {
        __syncthreads();
        #pragma unroll
        for (int q = 0; q < 2; ++q)
            *(float4*)&cps[tid*8 + q*4] =
                *(const float4*)(ws + WS_CP + ((size_t)b*Nn + tile*256)*8 + tid*8 + q*4);
        __syncthreads();
        for (int nn = g*64; nn < g*64 + 64; ++nn)
            s += cps[nn*8 + i]*cps[nn*8 + j];
    }
    Sred[g][pr] = s;
    if (tid < 64) Mlds[tid] = ws[WS_M + b*64 + tid];
    __syncthreads();
    if (tid < 64) Sfull[tid] = Sred[0][tid]+Sred[1][tid]+Sred[2][tid]+Sred[3][tid];
    __syncthreads();
    if (tid < 64) {
        int ii = tid >> 3, jj = tid & 7;
        float a = 0.f;
        #pragma unroll
        for (int k = 0; k < 8; ++k) a += Mlds[ii*8+k]*Sfull[k*8+jj];
        Alds[tid] = a;
    }
    __syncthreads();
    if (tid < 64) {
        float p = Alds[tid]*Alds[(tid & 7)*8 + (tid >> 3)];
        #pragma unroll
        for (int off = 32; off >= 1; off >>= 1) p += __shfl_xor(p, off, 64);
        if (tid == 0) ws[WS_TRB + b] = p;
    }
}

// ============ K7: finalize losses ============
__global__ __launch_bounds__(256) void k7_final(const float* __restrict__ ws,
                                                float* __restrict__ out_loss) {
    int tid = threadIdx.x, lane = tid & 63, wave = tid >> 6;
    __shared__ double red[4][4];
    double c = 0.0, dg = 0.0, as = 0.0, ac = 0.0;
    for (int idx = tid; idx < 512; idx += 256) {
        c  += (double)ws[WS_P5A + idx*2 + 0];
        dg += (double)ws[WS_P5A + idx*2 + 1];
        as += (double)ws[WS_P5B + idx*2 + 0];
        ac += (double)ws[WS_P5B + idx*2 + 1];
    }
    #pragma unroll
    for (int off = 32; off >= 1; off >>= 1) {
        c  += __shfl_xor(c,  off, 64);
        dg += __shfl_xor(dg, off, 64);
        as += __shfl_xor(as, off, 64);
        ac += __shfl_xor(ac, off, 64);
    }
    if (lane == 0) { red[wave][0]=c; red[wave][1]=dg; red[wave][2]=as; red[wave][3]=ac; }
    __syncthreads();
    if (tid == 0) {
        double ct=0, dgt=0, ast=0, act=0, trt=0;
        for (int w = 0; w < 4; ++w) { ct+=red[w][0]; dgt+=red[w][1]; ast+=red[w][2]; act+=red[w][3]; }
        for (int b = 0; b < Bb; ++b) trt += (double)ws[WS_TRB + b];
        out_loss[0] = (float)(ct / (double)((size_t)Bb*Nn));
        out_loss[1] = (float)((trt - dgt) / ((double)Bb*(double)Nn*(double)Nn));
        out_loss[2] = (float)(act > 0.0 ? ast / (act > 1.0 ? act : 1.0) : 0.0);
    }
}

extern "C" void kernel_launch(void* const* d_in, const int* in_sizes, int n_in,
                              void* d_out, int out_size, void* d_ws, size_t ws_size,
                              hipStream_t stream) {
    (void)in_sizes; (void)n_in; (void)out_size; (void)ws_size;
    const float* f_raw   = (const float*)d_in[0];
    const float* f_q     = (const float*)d_in[1];
    const int*   gt_mask = (const int*)d_in[2];
    const float* q_bg    = (const float*)d_in[3];
    const float* alpha   = (const float*)d_in[4];
    const float* ln_w    = (const float*)d_in[5];
    const float* ln_b    = (const float*)d_in[6];
    float* out = (float*)d_out;
    float* ws  = (float*)d_ws;

    k1_scores<<<512, 256, 0, stream>>>(f_raw, q_bg, ws);
    k2_softmax<<<Bb, 256, 0, stream>>>(ws);
    k3_pbpart<<<dim3(Bb, NSCH, 2), 256, 0, stream>>>(f_raw, ws);
    k3b_pbg<<<Bb, 256, 0, stream>>>(ws, out + OUT_PBG, f_q);
    k5a_scal<<<512, 256, 0, stream>>>(f_raw, alpha, out + OUT_PBG, ws);
    k5b_elem<<<512, 256, 0, stream>>>(f_raw, gt_mask, alpha, ln_w, ln_b,
                                      out + OUT_PBG, ws,
                                      out + OUT_FFG, out + OUT_FBG, out + OUT_SSEM);
    k6s_gram<<<Bb, 256, 0, stream>>>(ws);
    k7_final<<<1, 256, 0, stream>>>(ws, out + OUT_LOSS);
}

// Round 5
// 146.147 us; speedup vs baseline: 1.6235x; 1.2048x over previous
//
#include <hip/hip_runtime.h>
#include <math.h>

#define Bb 16
#define Nn 2048
#define Dd 512
#define Kk 8

constexpr float TAU = 0.07f;
constexpr float EPSc = 1e-6f;
constexpr float LN_EPS = 1e-5f;
constexpr float NORM_EPS = 1e-12f;
constexpr float SCALE = 0.04419417382415922f; // 1/sqrt(512)

// output layout (floats)
constexpr size_t OUT_FFG  = 0;
constexpr size_t OUT_FBG  = (size_t)Bb*Nn*Dd;
constexpr size_t OUT_PBG  = OUT_FBG + (size_t)Bb*Nn*Dd;
constexpr size_t OUT_SSEM = OUT_PBG + (size_t)Bb*Kk*Dd;
constexpr size_t OUT_LOSS = OUT_SSEM + (size_t)Bb*Nn;

// ws layout (floats)
constexpr size_t WS_PBPART = 0;                                 // B*32*K*D = 2,097,152
constexpr size_t WS_SUMW   = WS_PBPART + (size_t)Bb*32*Kk*Dd;   // B*32*8 = 4096
constexpr size_t WS_NF2    = WS_SUMW + (size_t)Bb*32*Kk;        // B*N
constexpr size_t WS_SF     = WS_NF2 + (size_t)Bb*Nn;            // B*N
constexpr size_t WS_M      = WS_SF + (size_t)Bb*Nn;             // B*64
constexpr size_t WS_IDEN   = WS_M + Bb*64;                      // B*K
constexpr size_t WS_INP    = WS_IDEN + Bb*Kk;                   // B*K
constexpr size_t WS_P1     = WS_INP + Bb*Kk;                    // B*K
constexpr size_t WS_FQN    = WS_P1 + Bb*Kk;                     // B*D
constexpr size_t WS_CP     = WS_FQN + (size_t)Bb*Dd;            // B*N*8
constexpr size_t WS_P5A    = WS_CP + (size_t)Bb*Nn*Kk;          // 512*2
constexpr size_t WS_P5B    = WS_P5A + 1024;                     // 512*2
constexpr size_t WS_TRB    = WS_P5B + 1024;                     // 16

__device__ __forceinline__ float dot4(float4 a, float4 b) {
    return a.x*b.x + a.y*b.y + a.z*b.z + a.w*b.w;
}

// ============ K1: scores + exp + p~ partials + sumw + nf2/sf ============
__global__ __launch_bounds__(256) void k1_scores(const float* __restrict__ f_raw,
                                                 const float* __restrict__ q_bg,
                                                 float* __restrict__ ws) {
    int b = blockIdx.x >> 5;
    int chunk = blockIdx.x & 31;
    int tok0 = chunk * 64;
    int tid = threadIdx.x, lane = tid & 63, wave = tid >> 6;
    __shared__ float tile[4][64*36];
    __shared__ float part[4][64][12];
    __shared__ float wlds[64][8];
    float* mt = tile[wave];
    int dw = __builtin_amdgcn_readfirstlane(wave * 128);
    const float* qb = q_bg + dw;                       // uniform base -> s_load
    const float* frow = f_raw + (size_t)b*Nn*Dd + dw;
    int tg = lane >> 3, c4 = (lane & 7) * 4;

    float acc[8] = {0,0,0,0,0,0,0,0};
    float nf2 = 0.f, sf = 0.f;
    float4 cur[8], nxt[8];
    #pragma unroll
    for (int i = 0; i < 8; ++i)
        cur[i] = *(const float4*)(frow + (size_t)(tok0 + i*8 + tg)*Dd + c4);
    #pragma unroll
    for (int sub = 0; sub < 4; ++sub) {
        if (sub < 3) {
            #pragma unroll
            for (int i = 0; i < 8; ++i)
                nxt[i] = *(const float4*)(frow + (size_t)(tok0 + i*8 + tg)*Dd + (sub+1)*32 + c4);
        }
        #pragma unroll
        for (int i = 0; i < 8; ++i)
            *(float4*)&mt[(i*8 + tg)*36 + c4] = cur[i];
        #pragma unroll
        for (int cc = 0; cc < 8; ++cc) {
            float4 f4 = *(const float4*)&mt[lane*36 + cc*4];
            const float* qd = qb + sub*32 + cc*4;
            #pragma unroll
            for (int k = 0; k < 8; ++k) {
                acc[k] += f4.x*qd[k*Dd+0] + f4.y*qd[k*Dd+1]
                        + f4.z*qd[k*Dd+2] + f4.w*qd[k*Dd+3];
            }
            nf2 += dot4(f4, f4);
            sf  += f4.x + f4.y + f4.z + f4.w;
        }
        if (sub < 3) {
            #pragma unroll
            for (int i = 0; i < 8; ++i) cur[i] = nxt[i];
        }
    }
    *(float4*)&part[wave][lane][0] = make_float4(acc[0],acc[1],acc[2],acc[3]);
    *(float4*)&part[wave][lane][4] = make_float4(acc[4],acc[5],acc[6],acc[7]);
    *(float2*)&part[wave][lane][8] = make_float2(nf2, sf);
    __syncthreads();
    if (wave == 0) {
        float a[8] = {0,0,0,0,0,0,0,0};
        float n2 = 0.f, s1 = 0.f;
        #pragma unroll
        for (int w = 0; w < 4; ++w) {
            float4 p0 = *(const float4*)&part[w][lane][0];
            float4 p1 = *(const float4*)&part[w][lane][4];
            float2 p2 = *(const float2*)&part[w][lane][8];
            a[0]+=p0.x; a[1]+=p0.y; a[2]+=p0.z; a[3]+=p0.w;
            a[4]+=p1.x; a[5]+=p1.y; a[6]+=p1.z; a[7]+=p1.w;
            n2 += p2.x; s1 += p2.y;
        }
        size_t n = (size_t)b*Nn + tok0 + lane;
        ws[WS_NF2 + n] = n2;
        ws[WS_SF + n]  = s1;
        float w8[8];
        #pragma unroll
        for (int k = 0; k < 8; ++k) w8[k] = expf(a[k]*SCALE);
        *(float4*)&wlds[lane][0] = make_float4(w8[0],w8[1],w8[2],w8[3]);
        *(float4*)&wlds[lane][4] = make_float4(w8[4],w8[5],w8[6],w8[7]);
        float sw[8];
        #pragma unroll
        for (int k = 0; k < 8; ++k) sw[k] = w8[k];
        #pragma unroll
        for (int off = 32; off >= 1; off >>= 1) {
            #pragma unroll
            for (int k = 0; k < 8; ++k) sw[k] += __shfl_xor(sw[k], off, 64);
        }
        if (lane == 0) {
            #pragma unroll
            for (int k = 0; k < 8; ++k)
                ws[WS_SUMW + (size_t)(b*32 + chunk)*8 + k] = sw[k];
        }
    }
    __syncthreads();
    // phase B: p~ partial accumulation, wave owns d-slice [wave*128, wave*128+128)
    int dbase = wave*128 + lane*2;
    const float* fcol = f_raw + ((size_t)b*Nn + tok0)*Dd + dbase;
    float accx[8] = {0,0,0,0,0,0,0,0};
    float accy[8] = {0,0,0,0,0,0,0,0};
    #pragma unroll 4
    for (int nn = 0; nn < 64; ++nn) {
        float2 f2 = *(const float2*)(fcol + (size_t)nn*Dd);
        float4 wa = *(const float4*)&wlds[nn][0];
        float4 wb = *(const float4*)&wlds[nn][4];
        accx[0]+=wa.x*f2.x; accx[1]+=wa.y*f2.x; accx[2]+=wa.z*f2.x; accx[3]+=wa.w*f2.x;
        accx[4]+=wb.x*f2.x; accx[5]+=wb.y*f2.x; accx[6]+=wb.z*f2.x; accx[7]+=wb.w*f2.x;
        accy[0]+=wa.x*f2.y; accy[1]+=wa.y*f2.y; accy[2]+=wa.z*f2.y; accy[3]+=wa.w*f2.y;
        accy[4]+=wb.x*f2.y; accy[5]+=wb.y*f2.y; accy[6]+=wb.z*f2.y; accy[7]+=wb.w*f2.y;
    }
    #pragma unroll
    for (int k = 0; k < 8; ++k)
        *(float2*)(ws + WS_PBPART + ((size_t)(b*32 + chunk)*8 + k)*Dd + dbase)
            = make_float2(accx[k], accy[k]);
}

// ============ K3b: reduce -> p_bg (normalized), M, iden, inp, P1, fqn ============
__global__ __launch_bounds__(256) void k3b_pbg(float* __restrict__ ws,
                                               float* __restrict__ out_pbg,
                                               const float* __restrict__ f_q) {
    int b = blockIdx.x, tid = threadIdx.x;
    int lane = tid & 63, wave = tid >> 6;
    __shared__ float pb[Kk*Dd];
    __shared__ float mseg[64][4];
    __shared__ float p1seg[8][8];
    __shared__ float red[4];
    __shared__ float swt[8];
    if (tid < 8) {
        float s = 0.f;
        #pragma unroll 8
        for (int ns = 0; ns < 32; ++ns)
            s += ws[WS_SUMW + (size_t)(b*32 + ns)*8 + tid];
        swt[tid] = 1.f/s;
    }
    __syncthreads();
    for (int e = tid; e < Kk*Dd; e += 256) {
        float s = 0.f;
        #pragma unroll 8
        for (int ns = 0; ns < 32; ++ns)
            s += ws[WS_PBPART + (size_t)(b*32 + ns)*(Kk*Dd) + e];
        s *= swt[e >> 9];
        pb[e] = s;
        out_pbg[(size_t)b*Kk*Dd + e] = s;
    }
    float q0 = f_q[b*Dd + tid], q1 = f_q[b*Dd + 256 + tid];
    float p2 = q0*q0 + q1*q1;
    #pragma unroll
    for (int off = 32; off >= 1; off >>= 1) p2 += __shfl_xor(p2, off, 64);
    if (lane == 0) red[wave] = p2;
    __syncthreads();
    float invq = 1.f/fmaxf(sqrtf(red[0]+red[1]+red[2]+red[3]), NORM_EPS);
    ws[WS_FQN + b*Dd + tid] = q0*invq;
    ws[WS_FQN + b*Dd + 256 + tid] = q1*invq;
    {
        int pair = tid >> 2, seg = tid & 3;
        int i = pair >> 3, j = pair & 7;
        float s = 0.f;
        for (int d = seg*128; d < seg*128 + 128; ++d) s += pb[i*Dd + d]*pb[j*Dd + d];
        mseg[pair][seg] = s;
    }
    if (tid < 64) {
        int k = tid >> 3, sg = tid & 7;
        float s1 = 0.f;
        for (int d = sg*64; d < sg*64 + 64; ++d) s1 += pb[k*Dd + d];
        p1seg[k][sg] = s1;
    }
    __syncthreads();
    if (tid < 64) {
        float m = mseg[tid][0] + mseg[tid][1] + mseg[tid][2] + mseg[tid][3];
        ws[WS_M + b*64 + tid] = m;
        if ((tid >> 3) == (tid & 7)) {
            int k = tid & 7;
            ws[WS_IDEN + b*Kk + k] = 1.f/(m + EPSc);
            ws[WS_INP + b*Kk + k] = 1.f/fmaxf(sqrtf(m), NORM_EPS);
        }
    }
    if (tid < 8) {
        float s1 = 0.f;
        #pragma unroll
        for (int sg = 0; sg < 8; ++sg) s1 += p1seg[tid][sg];
        ws[WS_P1 + b*Kk + tid] = s1;
    }
}

// ============ K5: fused per-token dots -> scalars -> elementwise ============
__global__ __launch_bounds__(256) void k5_main(
    const float* __restrict__ f_raw, const int* __restrict__ gt_mask,
    const float* __restrict__ alpha_p, const float* __restrict__ ln_w,
    const float* __restrict__ ln_b, const float* __restrict__ pbg,
    float* __restrict__ ws, float* __restrict__ out_ffg,
    float* __restrict__ out_fbg, float* __restrict__ out_ssem)
{
    int b = blockIdx.x >> 5;
    int chunk = blockIdx.x & 31;
    int tok0 = chunk * 64;
    int tid = threadIdx.x, lane = tid & 63, wave = tid >> 6;
    __shared__ float tile[4][64*36];
    __shared__ float part[4][64][8];
    __shared__ float scl[64][12];
    __shared__ float Ml[64];
    __shared__ float idenl[8], inpl[8], p1l[8];
    __shared__ float al[4][2];
    if (tid < 64) Ml[tid] = ws[WS_M + b*64 + tid];
    if (tid >= 64 && tid < 72) {
        int k = tid - 64;
        idenl[k] = ws[WS_IDEN + b*8 + k];
        inpl[k]  = ws[WS_INP + b*8 + k];
        p1l[k]   = ws[WS_P1 + b*8 + k];
    }
    float* mt = tile[wave];
    int dw = __builtin_amdgcn_readfirstlane(wave * 128);
    const float* pbb = pbg + (size_t)b*Kk*Dd + dw;      // uniform base
    const float* frow = f_raw + (size_t)b*Nn*Dd + dw;
    int tg = lane >> 3, c4 = (lane & 7) * 4;

    float acc[8] = {0,0,0,0,0,0,0,0};
    float4 cur[8], nxt[8];
    #pragma unroll
    for (int i = 0; i < 8; ++i)
        cur[i] = *(const float4*)(frow + (size_t)(tok0 + i*8 + tg)*Dd + c4);
    #pragma unroll
    for (int sub = 0; sub < 4; ++sub) {
        if (sub < 3) {
            #pragma unroll
            for (int i = 0; i < 8; ++i)
                nxt[i] = *(const float4*)(frow + (size_t)(tok0 + i*8 + tg)*Dd + (sub+1)*32 + c4);
        }
        #pragma unroll
        for (int i = 0; i < 8; ++i)
            *(float4*)&mt[(i*8 + tg)*36 + c4] = cur[i];
        #pragma unroll
        for (int cc = 0; cc < 8; ++cc) {
            float4 f4 = *(const float4*)&mt[lane*36 + cc*4];
            const float* pd = pbb + sub*32 + cc*4;
            #pragma unroll
            for (int k = 0; k < 8; ++k) {
                acc[k] += f4.x*pd[k*Dd+0] + f4.y*pd[k*Dd+1]
                        + f4.z*pd[k*Dd+2] + f4.w*pd[k*Dd+3];
            }
        }
        if (sub < 3) {
            #pragma unroll
            for (int i = 0; i < 8; ++i) cur[i] = nxt[i];
        }
    }
    *(float4*)&part[wave][lane][0] = make_float4(acc[0],acc[1],acc[2],acc[3]);
    *(float4*)&part[wave][lane][4] = make_float4(acc[4],acc[5],acc[6],acc[7]);
    __syncthreads();
    if (wave == 0) {
        float a[8] = {0,0,0,0,0,0,0,0};
        #pragma unroll
        for (int w = 0; w < 4; ++w) {
            float4 p0 = *(const float4*)&part[w][lane][0];
            float4 p1 = *(const float4*)&part[w][lane][4];
            a[0]+=p0.x; a[1]+=p0.y; a[2]+=p0.z; a[3]+=p0.w;
            a[4]+=p1.x; a[5]+=p1.y; a[6]+=p1.z; a[7]+=p1.w;
        }
        size_t n = (size_t)b*Nn + tok0 + lane;
        float nf2 = ws[WS_NF2 + n];
        float sf  = ws[WS_SF + n];
        float alpha = alpha_p[0];
        float coef[8], sca = 0.f, sp1 = 0.f;
        #pragma unroll
        for (int k = 0; k < 8; ++k) {
            coef[k] = a[k]*idenl[k];
            sca += coef[k]*a[k];
            sp1 += coef[k]*p1l[k];
        }
        float quad = 0.f;
        #pragma unroll
        for (int i = 0; i < 8; ++i) {
            float ti = 0.f;
            #pragma unroll
            for (int j = 0; j < 8; ++j) ti += Ml[i*8+j]*coef[j];
            quad += coef[i]*ti;
        }
        float sx  = sf - alpha*sp1;
        float sxx = nf2 - 2.f*alpha*sca + alpha*alpha*quad;
        float mu  = sx*(1.f/Dd);
        float var = sxx*(1.f/Dd) - mu*mu;
        float rstd = 1.f/sqrtf(fmaxf(var, 0.f) + LN_EPS);
        float invnf = 1.f/fmaxf(sqrtf(nf2), NORM_EPS);
        float cmin = 1e30f;
        #pragma unroll
        for (int k = 0; k < 8; ++k) cmin = fminf(cmin, 1.f - a[k]*invnf*inpl[k]);
        float invnb = 1.f/fmaxf(sqrtf(quad), NORM_EPS);
        float inb2 = invnb*invnb;
        float gnn = quad*inb2;
        float dsum = gnn*gnn;
        *(float4*)&scl[lane][0] = make_float4(coef[0],coef[1],coef[2],coef[3]);
        *(float4*)&scl[lane][4] = make_float4(coef[4],coef[5],coef[6],coef[7]);
        *(float2*)&scl[lane][8] = make_float2(mu, rstd);
        *(float4*)(ws + WS_CP + n*8)     = make_float4(coef[0]*invnb,coef[1]*invnb,coef[2]*invnb,coef[3]*invnb);
        *(float4*)(ws + WS_CP + n*8 + 4) = make_float4(coef[4]*invnb,coef[5]*invnb,coef[6]*invnb,coef[7]*invnb);
        float csum = cmin;
        #pragma unroll
        for (int off = 32; off >= 1; off >>= 1) {
            csum += __shfl_xor(csum, off, 64);
            dsum += __shfl_xor(dsum, off, 64);
        }
        if (lane == 0) {
            ws[WS_P5A + (size_t)blockIdx.x*2 + 0] = csum;
            ws[WS_P5A + (size_t)blockIdx.x*2 + 1] = dsum;
        }
    }
    __syncthreads();
    // phase B: elementwise fb / LN / g / ssem
    int d0 = lane*4, d1 = 256 + lane*4;
    float4 pbr[8][2];
    #pragma unroll
    for (int k = 0; k < 8; ++k) {
        pbr[k][0] = *(const float4*)(pbg + (size_t)b*Kk*Dd + k*Dd + d0);
        pbr[k][1] = *(const float4*)(pbg + (size_t)b*Kk*Dd + k*Dd + d1);
    }
    float4 w0 = *(const float4*)(ln_w + d0), w1 = *(const float4*)(ln_w + d1);
    float4 b0 = *(const float4*)(ln_b + d0), b1 = *(const float4*)(ln_b + d1);
    float4 q0 = *(const float4*)(ws + WS_FQN + b*Dd + d0);
    float4 q1 = *(const float4*)(ws + WS_FQN + b*Dd + d1);
    float alpha = alpha_p[0];
    float align_s = 0.f, align_c = 0.f;
    for (int t = 0; t < 16; ++t) {
        int lt = wave*16 + t;
        int tok = tok0 + lt;
        size_t n = (size_t)b*Nn + tok;
        float4 cA = *(const float4*)&scl[lt][0];
        float4 cB = *(const float4*)&scl[lt][4];
        float2 mr = *(const float2*)&scl[lt][8];
        float muv = mr.x, rstd = mr.y;
        size_t rowoff = n*(size_t)Dd;
        float4 fv0 = *(const float4*)(f_raw + rowoff + d0);
        float4 fv1 = *(const float4*)(f_raw + rowoff + d1);
        float ng2 = 0.f, dq = 0.f;
        {
            float4 fb = {0,0,0,0};
            fb.x = cA.x*pbr[0][0].x + cA.y*pbr[1][0].x + cA.z*pbr[2][0].x + cA.w*pbr[3][0].x
                 + cB.x*pbr[4][0].x + cB.y*pbr[5][0].x + cB.z*pbr[6][0].x + cB.w*pbr[7][0].x;
            fb.y = cA.x*pbr[0][0].y + cA.y*pbr[1][0].y + cA.z*pbr[2][0].y + cA.w*pbr[3][0].y
                 + cB.x*pbr[4][0].y + cB.y*pbr[5][0].y + cB.z*pbr[6][0].y + cB.w*pbr[7][0].y;
            fb.z = cA.x*pbr[0][0].z + cA.y*pbr[1][0].z + cA.z*pbr[2][0].z + cA.w*pbr[3][0].z
                 + cB.x*pbr[4][0].z + cB.y*pbr[5][0].z + cB.z*pbr[6][0].z + cB.w*pbr[7][0].z;
            fb.w = cA.x*pbr[0][0].w + cA.y*pbr[1][0].w + cA.z*pbr[2][0].w + cA.w*pbr[3][0].w
                 + cB.x*pbr[4][0].w + cB.y*pbr[5][0].w + cB.z*pbr[6][0].w + cB.w*pbr[7][0].w;
            *(float4*)(out_fbg + rowoff + d0) = fb;
            float4 g;
            g.x = (fv0.x - alpha*fb.x - muv)*rstd*w0.x + b0.x;
            g.y = (fv0.y - alpha*fb.y - muv)*rstd*w0.y + b0.y;
            g.z = (fv0.z - alpha*fb.z - muv)*rstd*w0.z + b0.z;
            g.w = (fv0.w - alpha*fb.w - muv)*rstd*w0.w + b0.w;
            *(float4*)(out_ffg + rowoff + d0) = g;
            ng2 += dot4(g, g); dq += dot4(g, q0);
        }
        {
            float4 fb = {0,0,0,0};
            fb.x = cA.x*pbr[0][1].x + cA.y*pbr[1][1].x + cA.z*pbr[2][1].x + cA.w*pbr[3][1].x
                 + cB.x*pbr[4][1].x + cB.y*pbr[5][1].x + cB.z*pbr[6][1].x + cB.w*pbr[7][1].x;
            fb.y = cA.x*pbr[0][1].y + cA.y*pbr[1][1].y + cA.z*pbr[2][1].y + cA.w*pbr[3][1].y
                 + cB.x*pbr[4][1].y + cB.y*pbr[5][1].y + cB.z*pbr[6][1].y + cB.w*pbr[7][1].y;
            fb.z = cA.x*pbr[0][1].z + cA.y*pbr[1][1].z + cA.z*pbr[2][1].z + cA.w*pbr[3][1].z
                 + cB.x*pbr[4][1].z + cB.y*pbr[5][1].z + cB.z*pbr[6][1].z + cB.w*pbr[7][1].z;
            fb.w = cA.x*pbr[0][1].w + cA.y*pbr[1][1].w + cA.z*pbr[2][1].w + cA.w*pbr[3][1].w
                 + cB.x*pbr[4][1].w + cB.y*pbr[5][1].w + cB.z*pbr[6][1].w + cB.w*pbr[7][1].w;
            *(float4*)(out_fbg + rowoff + d1) = fb;
            float4 g;
            g.x = (fv1.x - alpha*fb.x - muv)*rstd*w1.x + b1.x;
            g.y = (fv1.y - alpha*fb.y - muv)*rstd*w1.y + b1.y;
            g.z = (fv1.z - alpha*fb.z - muv)*rstd*w1.z + b1.z;
            g.w = (fv1.w - alpha*fb.w - muv)*rstd*w1.w + b1.w;
            *(float4*)(out_ffg + rowoff + d1) = g;
            ng2 += dot4(g, g); dq += dot4(g, q1);
        }
        #pragma unroll
        for (int off = 32; off >= 1; off >>= 1) {
            ng2 += __shfl_xor(ng2, off, 64);
            dq  += __shfl_xor(dq,  off, 64);
        }
        float sim = dq * (1.f/fmaxf(sqrtf(ng2), NORM_EPS));
        float ssem = 1.f/(1.f + expf(-sim*(1.f/TAU)));
        if (lane == 0) {
            out_ssem[n] = ssem;
            if (gt_mask[n] != 0) { align_s += -logf(fmaxf(ssem, EPSc)); align_c += 1.f; }
        }
    }
    if (lane == 0) { al[wave][0] = align_s; al[wave][1] = align_c; }
    __syncthreads();
    if (tid == 0) {
        ws[WS_P5B + (size_t)blockIdx.x*2 + 0] = al[0][0]+al[1][0]+al[2][0]+al[3][0];
        ws[WS_P5B + (size_t)blockIdx.x*2 + 1] = al[0][1]+al[1][1]+al[2][1]+al[3][1];
    }
}

// ============ K6s: per-batch S = sum cp cp^T, then tr((M S)^2) ============
__global__ __launch_bounds__(256) void k6s_gram(float* __restrict__ ws) {
    int b = blockIdx.x, tid = threadIdx.x;
    __shared__ float cps[256*8];
    __shared__ float Sred[4][64];
    __shared__ float Sfull[64];
    __shared__ float Alds[64];
    __shared__ float Mlds[64];
    int pr = tid & 63, g = tid >> 6;
    int i = pr >> 3, j = pr & 7;
    float s = 0.f;
    for (int tile = 0; tile < 8; ++tile) {
        __syncthreads();
        #pragma unroll
        for (int q = 0; q < 2; ++q)
            *(float4*)&cps[tid*8 + q*4] =
                *(const float4*)(ws + WS_CP + ((size_t)b*Nn + tile*256)*8 + tid*8 + q*4);
        __syncthreads();
        for (int nn = g*64; nn < g*64 + 64; ++nn)
            s += cps[nn*8 + i]*cps[nn*8 + j];
    }
    Sred[g][pr] = s;
    if (tid < 64) Mlds[tid] = ws[WS_M + b*64 + tid];
    __syncthreads();
    if (tid < 64) Sfull[tid] = Sred[0][tid]+Sred[1][tid]+Sred[2][tid]+Sred[3][tid];
    __syncthreads();
    if (tid < 64) {
        int ii = tid >> 3, jj = tid & 7;
        float a = 0.f;
        #pragma unroll
        for (int k = 0; k < 8; ++k) a += Mlds[ii*8+k]*Sfull[k*8+jj];
        Alds[tid] = a;
    }
    __syncthreads();
    if (tid < 64) {
        float p = Alds[tid]*Alds[(tid & 7)*8 + (tid >> 3)];
        #pragma unroll
        for (int off = 32; off >= 1; off >>= 1) p += __shfl_xor(p, off, 64);
        if (tid == 0) ws[WS_TRB + b] = p;
    }
}

// ============ K7: finalize losses ============
__global__ __launch_bounds__(256) void k7_final(const float* __restrict__ ws,
                                                float* __restrict__ out_loss) {
    int tid = threadIdx.x, lane = tid & 63, wave = tid >> 6;
    __shared__ double red[4][4];
    double c = 0.0, dg = 0.0, as = 0.0, ac = 0.0;
    for (int idx = tid; idx < 512; idx += 256) {
        c  += (double)ws[WS_P5A + idx*2 + 0];
        dg += (double)ws[WS_P5A + idx*2 + 1];
        as += (double)ws[WS_P5B + idx*2 + 0];
        ac += (double)ws[WS_P5B + idx*2 + 1];
    }
    #pragma unroll
    for (int off = 32; off >= 1; off >>= 1) {
        c  += __shfl_xor(c,  off, 64);
        dg += __shfl_xor(dg, off, 64);
        as += __shfl_xor(as, off, 64);
        ac += __shfl_xor(ac, off, 64);
    }
    if (lane == 0) { red[wave][0]=c; red[wave][1]=dg; red[wave][2]=as; red[wave][3]=ac; }
    __syncthreads();
    if (tid == 0) {
        double ct=0, dgt=0, ast=0, act=0, trt=0;
        for (int w = 0; w < 4; ++w) { ct+=red[w][0]; dgt+=red[w][1]; ast+=red[w][2]; act+=red[w][3]; }
        for (int b = 0; b < Bb; ++b) trt += (double)ws[WS_TRB + b];
        out_loss[0] = (float)(ct / (double)((size_t)Bb*Nn));
        out_loss[1] = (float)((trt - dgt) / ((double)Bb*(double)Nn*(double)Nn));
        out_loss[2] = (float)(act > 0.0 ? ast / (act > 1.0 ? act : 1.0) : 0.0);
    }
}

extern "C" void kernel_launch(void* const* d_in, const int* in_sizes, int n_in,
                              void* d_out, int out_size, void* d_ws, size_t ws_size,
                              hipStream_t stream) {
    (void)in_sizes; (void)n_in; (void)out_size; (void)ws_size;
    const float* f_raw   = (const float*)d_in[0];
    const float* f_q     = (const float*)d_in[1];
    const int*   gt_mask = (const int*)d_in[2];
    const float* q_bg    = (const float*)d_in[3];
    const float* alpha   = (const float*)d_in[4];
    const float* ln_w    = (const float*)d_in[5];
    const float* ln_b    = (const float*)d_in[6];
    float* out = (float*)d_out;
    float* ws  = (float*)d_ws;

    k1_scores<<<512, 256, 0, stream>>>(f_raw, q_bg, ws);
    k3b_pbg<<<Bb, 256, 0, stream>>>(ws, out + OUT_PBG, f_q);
    k5_main<<<512, 256, 0, stream>>>(f_raw, gt_mask, alpha, ln_w, ln_b,
                                     out + OUT_PBG, ws,
                                     out + OUT_FFG, out + OUT_FBG, out + OUT_SSEM);
    k6s_gram<<<Bb, 256, 0, stream>>>(ws);
    k7_final<<<1, 256, 0, stream>>>(ws, out + OUT_LOSS);
}